// Round 8
// baseline (130.539 us; speedup 1.0000x reference)
//
#include <hip/hip_runtime.h>

// FreqLinear: out = Y2 @ float(idx)^T + corr[m] + bias[o], K = 2048.
// GEMM v8: ASYNC global_load_lds staging (uncollapsible prefetch) + wave
// specialization + raw-int LDS ring.
//   Rounds 2/6/7 all failed the same way: the compiler sinks register-held
//   prefetch loads to their uses (R6 VGPR_Count=88 vs 128+ needed), exposing
//   full HBM latency per chunk. global_load_lds has NO destination register
//   -> cannot be collapsed; prefetch depth is structural.
// Block = 384 thr: waves 4..5 = producers, waves 0..3 = consumers.
//   Producers: per chunk issue 16x global_load_lds (1 KB each: one col's 256
//     raw ints -> LDS region (c&3), col stride 1040 B), 2 chunks ahead;
//     s_waitcnt vmcnt(32) (prefetch stays in flight) -> volatile flag.
//     Poll consumer done[c-2] before reusing a ring region.
//   Consumers (4 waves x 4 mg x 2 g): poll flags, ds_read raw ints,
//     cvt int->bf16 in-register (exact, values<=255), MFMA. Own vmcnt queue
//     holds only L2-hot A-loads (distance-2 kstep double buffer).
// LDS: 4 x 33280 B ring (+flags) = ~130 KB -> 1 block/CU, grid 256.

typedef __attribute__((ext_vector_type(8))) short bf16x8;   // 8 bf16
typedef __attribute__((ext_vector_type(4))) float f32x4;

#define K_TOT   2048
#define N_TOT   8192
#define NT      32        // cols per block
#define NCHUNK  8         // K chunks of 256
#define SPC     8         // ksteps (K=32) per chunk
#define COL_STR 1040      // col stride in LDS region (padded: 1024+16)
#define REG_SZ  (NT * COL_STR)   // 33280 B per ring region

__device__ __forceinline__ unsigned short f2bf_rn(float f) {
    unsigned u = __float_as_uint(f);
    u += 0x7FFFu + ((u >> 16) & 1u);
    return (unsigned short)(u >> 16);
}
// two ints (0..255) -> exact floats -> packed bf16 pair (truncation exact)
__device__ __forceinline__ unsigned pack2(int a, int b) {
    unsigned ua = __float_as_uint((float)a);
    unsigned ub = __float_as_uint((float)b);
    return __builtin_amdgcn_perm(ub, ua, 0x07060302u);
}
__device__ __forceinline__ bf16x8 cvt8(int4 lo, int4 hi) {
    union { unsigned u[4]; bf16x8 v; } r;
    r.u[0] = pack2(lo.x, lo.y);
    r.u[1] = pack2(lo.z, lo.w);
    r.u[2] = pack2(hi.x, hi.y);
    r.u[3] = pack2(hi.z, hi.w);
    return r.v;
}

__device__ __forceinline__ void lds_barrier() {
    asm volatile("" ::: "memory");
    __builtin_amdgcn_s_waitcnt(0xC07F);   // lgkmcnt(0) only
    __builtin_amdgcn_s_barrier();
    asm volatile("" ::: "memory");
}

// async 16B/lane global->LDS; gp is per-lane, lp must be wave-uniform
__device__ __forceinline__ void async16(const int* gp, char* lp) {
    __builtin_amdgcn_global_load_lds(
        (const __attribute__((address_space(1))) unsigned int*)gp,
        (__attribute__((address_space(3))) unsigned int*)lp, 16, 0, 0);
}

// ---------------- Kernel A: build Y2f (bf16, frag order) + corr ------------
__global__ __launch_bounds__(256) void prep_kernel(
    const float* __restrict__ x, const float* __restrict__ c_min,
    const float* __restrict__ c_range, unsigned short* __restrict__ Y2f,
    float* __restrict__ corr)
{
    __shared__ float Bk[8][16];
    __shared__ float scmin[8];
    __shared__ float ss[8];
    __shared__ float red[4];
    const int tid = threadIdx.x;
    const int m = blockIdx.x;
    if (tid < 128) {
        int k = tid >> 4, t = tid & 15;
        float v = cosf(3.14159265358979f * (t + 0.5f) * (float)k / 16.0f)
                  * 0.353553390593274f;                 // sqrt(2/16)
        if (k == 0) v *= 0.707106781186548f;            // 1/sqrt(2)
        Bk[k][t] = v;
    }
    if (tid < 8) {
        scmin[tid] = c_min[tid];
        ss[tid] = c_range[tid] * (1.0f / 255.0f);
    }
    __syncthreads();

    const float* xp = x + (long)m * 4096 + tid * 16;
    float xs[16];
#pragma unroll
    for (int q = 0; q < 4; ++q) {
        float4 v = *(const float4*)(xp + q * 4);
        xs[q * 4 + 0] = v.x; xs[q * 4 + 1] = v.y;
        xs[q * 4 + 2] = v.z; xs[q * 4 + 3] = v.w;
    }
    float partial = 0.0f;
    unsigned short yo[8];
#pragma unroll
    for (int k = 0; k < 8; ++k) {
        float y = 0.0f;
#pragma unroll
        for (int t = 0; t < 16; ++t) y += xs[t] * Bk[k][t];
        partial += y * scmin[k];
        yo[k] = f2bf_rn(y * ss[k]);
    }
    uint4 pk;
    pk.x = (unsigned)yo[0] | ((unsigned)yo[1] << 16);
    pk.y = (unsigned)yo[2] | ((unsigned)yo[3] << 16);
    pk.z = (unsigned)yo[4] | ((unsigned)yo[5] << 16);
    pk.w = (unsigned)yo[6] | ((unsigned)yo[7] << 16);
    // frag-order store: kc = tid>>2, fq = tid&3, mg = m>>4, fr = m&15
    {
        const int mg = m >> 4, fr = m & 15, kc = tid >> 2, fq = tid & 3;
        unsigned short* dst = Y2f + ((long)((mg * 64 + kc) * 64) + fq * 16 + fr) * 8;
        *(uint4*)dst = pk;
    }
#pragma unroll
    for (int off = 32; off > 0; off >>= 1)
        partial += __shfl_down(partial, off, 64);
    if ((tid & 63) == 0) red[tid >> 6] = partial;
    __syncthreads();
    if (tid == 0) corr[m] = red[0] + red[1] + red[2] + red[3];
}

// ---------------- Kernel B ------------------------------------------------
__global__ __launch_bounds__(384, 1) void gemm_kernel(
    const unsigned short* __restrict__ Y2f, const int* __restrict__ idx,
    const float* __restrict__ bias, const float* __restrict__ corr,
    float* __restrict__ out)
{
    __shared__ char lds[4 * REG_SZ];          // raw-int ring, ~130 KB
    __shared__ int flags[NCHUNK][2];          // producer-ready per chunk
    __shared__ int done[NCHUNK][4];           // consumer-done per chunk

    const int tid  = threadIdx.x;
    const int wave = tid >> 6;
    const int lane = tid & 63;
    const int o0   = blockIdx.x * NT;

    if (tid < NCHUNK * 2) flags[tid >> 1][tid & 1] = 0;
    if (tid < NCHUNK * 4) done[tid >> 2][tid & 3] = 0;

    if (wave >= 4) {
        // ================= PRODUCER (waves 4..5) ===========================
        const int pw = wave - 4;              // 0..1; cols [pw*16, pw*16+16)
        const int c0 = pw * 16;
        const int* gBase = idx + (long)(o0 + c0) * K_TOT + lane * 4;
        char* lBase = lds;

#define STAGE(ch)                                                         \
        {                                                                 \
            char* reg = lBase + ((ch) & 3) * REG_SZ + c0 * COL_STR;       \
            _Pragma("unroll")                                             \
            for (int l = 0; l < 16; ++l)                                  \
                async16(gBase + (long)l * K_TOT + (ch) * 256,             \
                        reg + l * COL_STR);                               \
        }

        STAGE(0)
        STAGE(1)
        lds_barrier();      // flag/done init visible

#pragma unroll
        for (int c = 0; c < NCHUNK; ++c) {
            if (c + 2 < NCHUNK) {
                if (c + 2 >= 4) {
                    // ring reuse: wait consumers done with chunk c-2
                    while (!(*(volatile int*)&done[c - 2][0] &
                             *(volatile int*)&done[c - 2][1] &
                             *(volatile int*)&done[c - 2][2] &
                             *(volatile int*)&done[c - 2][3]))
                        __builtin_amdgcn_s_sleep(1);
                    asm volatile("" ::: "memory");
                }
                STAGE(c + 2)
            }
            // wait chunk c landed; chunks c+1/c+2 (16 each) stay in flight
            if (c < NCHUNK - 2)      asm volatile("s_waitcnt vmcnt(32)" ::: "memory");
            else if (c == NCHUNK - 2) asm volatile("s_waitcnt vmcnt(16)" ::: "memory");
            else                      asm volatile("s_waitcnt vmcnt(0)"  ::: "memory");
            if (lane == 0) *(volatile int*)&flags[c][pw] = 1;
        }
#undef STAGE
    } else {
        // ================= CONSUMER (waves 0..3) ===========================
        const int fr = lane & 15;
        const int fq = lane >> 4;
        // A frags: mg = wave*4 + mt; frag(mg,ks) at bf16x8 idx mg*4096+ks*64+lane
        const bf16x8* aF = (const bf16x8*)Y2f + (long)(wave * 4) * 4096 + lane;

        f32x4 acc[4][2];
#pragma unroll
        for (int mt = 0; mt < 4; ++mt)
#pragma unroll
            for (int g = 0; g < 2; ++g)
                acc[mt][g] = (f32x4){0.f, 0.f, 0.f, 0.f};

        bf16x8 a[2][4];    // kstep double-buffer x 4 mg
#pragma unroll
        for (int mt = 0; mt < 4; ++mt) {
            a[0][mt] = aF[mt * 4096 + 0 * 64];
            a[1][mt] = aF[mt * 4096 + 1 * 64];
        }

        lds_barrier();

        // per-lane byte offsets of the two B cols (g=0,1) within a region
        const int bo0 = fr * COL_STR + fq * 32;
        const int bo1 = (16 + fr) * COL_STR + fq * 32;

#pragma unroll
        for (int c = 0; c < NCHUNK; ++c) {
            while (!(*(volatile int*)&flags[c][0] &
                     *(volatile int*)&flags[c][1]))
                __builtin_amdgcn_s_sleep(1);
            asm volatile("" ::: "memory");
            const char* buf = lds + (c & 3) * REG_SZ;
#pragma unroll
            for (int s = 0; s < SPC; ++s) {
                const char* p0 = buf + bo0 + s * 128;
                const char* p1 = buf + bo1 + s * 128;
                bf16x8 b0 = cvt8(*(const int4*)p0, *(const int4*)(p0 + 16));
                bf16x8 b1 = cvt8(*(const int4*)p1, *(const int4*)(p1 + 16));
#pragma unroll
                for (int mt = 0; mt < 4; ++mt) {
                    acc[mt][0] = __builtin_amdgcn_mfma_f32_16x16x32_bf16(
                        a[s & 1][mt], b0, acc[mt][0], 0, 0, 0);
                    acc[mt][1] = __builtin_amdgcn_mfma_f32_16x16x32_bf16(
                        a[s & 1][mt], b1, acc[mt][1], 0, 0, 0);
                }
                // refill used slot with kstep ks+2 (clamped at tail)
                {
                    const int ks = c * SPC + s;
                    const int nks = (ks + 2 < 64) ? ks + 2 : 63;
#pragma unroll
                    for (int mt = 0; mt < 4; ++mt)
                        a[s & 1][mt] = aF[mt * 4096 + nks * 64];
                }
            }
            asm volatile("s_waitcnt lgkmcnt(0)" ::: "memory");
            if (lane == 0) *(volatile int*)&done[c][wave] = 1;
        }

        // epilogue: D layout col=lane&15, row=(lane>>4)*4+reg
#pragma unroll
        for (int mt = 0; mt < 4; ++mt) {
#pragma unroll
            for (int g = 0; g < 2; ++g) {
                const int col = o0 + g * 16 + fr;
                const float bv = bias[col];
                const int row0 = (wave * 4 + mt) * 16 + fq * 4;
#pragma unroll
                for (int r = 0; r < 4; ++r)
                    out[(long)(row0 + r) * N_TOT + col] =
                        acc[mt][g][r] + bv + corr[row0 + r];
            }
        }
    }
}

extern "C" void kernel_launch(void* const* d_in, const int* in_sizes, int n_in,
                              void* d_out, int out_size, void* d_ws, size_t ws_size,
                              hipStream_t stream) {
    const float* x       = (const float*)d_in[0];   // [32,8,4096]
    const int*   idx     = (const int*)d_in[1];     // [2097152, 8]
    const float* c_min   = (const float*)d_in[2];   // [8]
    const float* c_range = (const float*)d_in[3];   // [8]
    const float* bias    = (const float*)d_in[4];   // [8192]
    float* out = (float*)d_out;                     // [256, 8192]

    unsigned short* Y2f = (unsigned short*)d_ws;                   // 1 MB
    float* corr = (float*)((char*)d_ws + (size_t)256 * K_TOT * 2); // 256 fp32

    prep_kernel<<<256, 256, 0, stream>>>(x, c_min, c_range, Y2f, corr);
    gemm_kernel<<<256, 384, 0, stream>>>(Y2f, idx, bias, corr, out);
}